// Round 5
// baseline (252.723 us; speedup 1.0000x reference)
//
#include <hip/hip_runtime.h>

// out[n, t] = sum_{j <= t} W[t, j] * x[n, j] + b[t]
// B = 1048576, T = 32, fp32. HBM floor ~41-43 us/dispatch.
//
// R5 == R3 resubmission #2 (R3: container failed twice; R4: GPU acquisition
// timeout -- both infra, zero kernel signal; hazard audit clean).
// Rationale: R1/R2 proved the kernel is NOT LDS/VALU/BW-bound (85-89 us,
// no pipe >35%) -- it is phase-serialization bound: short-lived blocks, full
// vmcnt(0) drain at every __syncthreads, 16 sequential block-generations/CU.
// Fix: persistent blocks (512 blocks x 8 tiles), double-buffered LDS,
// counted s_waitcnt vmcnt(8) so the next tile's global_load_lds stay in
// flight across raw s_barriers (T3/T4 pattern). Compute = R1's scalar-W
// triangle (verified). Layout = R2's XOR-swizzled float4 (verified).

constexpr int T         = 32;
constexpr int ROWS      = 256;   // rows per tile == block size (1 thread/row)
constexpr int TPB_TILES = 8;     // tiles per persistent block

__global__ __launch_bounds__(256) void triu_kernel(
    const float* __restrict__ x, const float* __restrict__ W,
    const float* __restrict__ b, float* __restrict__ out)
{
    __shared__ float4 sX[2][ROWS * 8];   // 2 x 32 KiB -> 2 blocks/CU

    const int tid  = threadIdx.x;
    const int lane = tid & 63;
    const int wid  = tid >> 6;
    const int r7   = tid & 7;

    const float4* __restrict__ x4 = reinterpret_cast<const float4*>(x);
    float4*       __restrict__ o4 = reinterpret_cast<float4*>(out);

    const long long tile0 = (long long)blockIdx.x * TPB_TILES;

    // Per-lane source offset inside a tile (float4 units), it-independent:
    // slot s = it*256 + wid*64 + lane receives chunk (row = s>>3,
    // c = (s&7)^(row&7)); row&7 reduces to lane>>3, so
    // addr = it*256 + wid*64 + (lane>>3)*8 + ((lane&7)^(lane>>3)).
    const int lrow = lane >> 3;
    const int lsrc = wid * 64 + lrow * 8 + ((lane & 7) ^ lrow);

    #define STAGE(g, buf)                                                     \
        do {                                                                  \
            const float4* _src = x4 + (tile0 + (g)) * (ROWS * 8) + lsrc;      \
            _Pragma("unroll")                                                 \
            for (int it = 0; it < 8; ++it) {                                  \
                __builtin_amdgcn_global_load_lds(                             \
                    (const __attribute__((address_space(1))) void*)(_src + it * 256), \
                    (__attribute__((address_space(3))) void*)(&sX[(buf)][it * 256 + wid * 64]), \
                    16, 0, 0);                                                \
            }                                                                 \
        } while (0)

    STAGE(0, 0);

    for (int i = 0; i < TPB_TILES; ++i) {
        const int cur = i & 1;

        // Wait for tile i's 8 loads (issued last iter, before stores_{i-1}).
        // vmcnt retires in order: <=8 outstanding => loads_i done, while the
        // stores of iter i-1 may still be in flight (never drain to 0).
        if (i == 0) { asm volatile("s_waitcnt vmcnt(0)" ::: "memory"); }
        else        { asm volatile("s_waitcnt vmcnt(8)" ::: "memory"); }
        __builtin_amdgcn_sched_barrier(0);
        __builtin_amdgcn_s_barrier();
        // All waves passed: tile i fully in LDS; all stage-out reads of
        // tile i-1 (same parity as i+1) completed before their dependent
        // stores issued, and stores issued before the barrier -> safe to
        // prefetch into buf cur^1 now.

        if (i + 1 < TPB_TILES) STAGE(i + 1, cur ^ 1);

        // This thread's row: 8 x ds_read_b128, XOR-inverted (involution).
        float xr[T];
        #pragma unroll
        for (int k = 0; k < 8; ++k) {
            const float4 v = sX[cur][tid * 8 + (k ^ r7)];
            xr[4*k+0] = v.x; xr[4*k+1] = v.y; xr[4*k+2] = v.z; xr[4*k+3] = v.w;
        }

        // Triangular FMA; W/b wave-uniform -> s_load + SGPR operand (R1-proven).
        float acc[T];
        #pragma unroll
        for (int t = 0; t < T; ++t) {
            float a = b[t];
            #pragma unroll
            for (int j = 0; j <= t; ++j)
                a = fmaf(W[t * T + j], xr[j], a);
            acc[t] = a;
        }

        // Writeback own row (only this thread touched these slots).
        #pragma unroll
        for (int k = 0; k < 8; ++k)
            sX[cur][tid * 8 + (k ^ r7)] =
                make_float4(acc[4*k+0], acc[4*k+1], acc[4*k+2], acc[4*k+3]);

        // LDS-only fence before the cross-thread stage-out reads.
        asm volatile("s_waitcnt lgkmcnt(0)" ::: "memory");
        __builtin_amdgcn_sched_barrier(0);
        __builtin_amdgcn_s_barrier();

        // Coalesced stage-out; stores join the vmcnt queue behind the
        // tile i+1 prefetch loads.
        float4* dst = o4 + (tile0 + i) * (ROWS * 8);
        #pragma unroll
        for (int it = 0; it < 8; ++it) {
            const int idx = it * 256 + tid;
            const int row = idx >> 3;
            dst[idx] = sX[cur][row * 8 + ((idx & 7) ^ (row & 7))];
        }
    }
    #undef STAGE
}

extern "C" void kernel_launch(void* const* d_in, const int* in_sizes, int n_in,
                              void* d_out, int out_size, void* d_ws, size_t ws_size,
                              hipStream_t stream) {
    const float* x  = (const float*)d_in[0];   // [B, 32]
    const float* W  = (const float*)d_in[1];   // [32, 32] (lower-tri used)
    const float* b  = (const float*)d_in[2];   // [32]
    float* out      = (float*)d_out;           // [B, 32]

    const int batch = in_sizes[0] / T;                 // 1048576
    const int grid  = batch / (ROWS * TPB_TILES);      // 512 persistent blocks
    triu_kernel<<<grid, 256, 0, stream>>>(x, W, b, out);
}

// Round 6
// 242.870 us; speedup vs baseline: 1.0406x; 1.0406x over previous
//
#include <hip/hip_runtime.h>

// out[n, t] = sum_{j <= t} W[t, j] * x[n, j] + b[t]
// B = 1048576, T = 32, fp32. Effective HBM floor ~200 MB -> ~35-43 us.
//
// R6: barrier-free wave-private staging. Evidence: R2 (34% occ, 89us) vs
// R5 (18.5% occ, 109us) -> latency-bound, TLP-limited; block-wide barriers
// phase-lock the 4 waves and cap useful concurrency. Fix: wave wid stages
// ITS OWN 64 rows into a private 8KB LDS slice; all __syncthreads removed.
//  - stage-in: global_load_lds w16, pre-swizzled global source (R2 layout),
//    per-wave s_waitcnt vmcnt(0) only.
//  - writeback + stage-out: wave-synchronous ds ops, lgkmcnt(0) only.
//  - 32 KB/block -> 5 blocks/CU = 20 decoupled waves/CU (62% occ).
// Compute: R1's scalar-W triangle (s_load -> SGPR FMA operand, verified).

constexpr int T    = 32;
constexpr int ROWS = 256;          // rows per block; 64 per wave

__global__ __launch_bounds__(256) void triu_kernel(
    const float* __restrict__ x, const float* __restrict__ W,
    const float* __restrict__ b, float* __restrict__ out)
{
    __shared__ float4 sX[ROWS * 8];    // 32 KiB; wave wid owns sX[wid*512 ..]

    const int tid  = threadIdx.x;
    const int lane = tid & 63;
    const int wid  = tid >> 6;

    const float4* __restrict__ x4 = reinterpret_cast<const float4*>(x);
    float4*       __restrict__ o4 = reinterpret_cast<float4*>(out);

    // This wave's 64-row panel (512 float4 = 8 KB).
    const long long wrow0 = (long long)blockIdx.x * ROWS + wid * 64;
    const float4* __restrict__ src0 = x4 + wrow0 * 8;
    float4*       __restrict__ dst0 = o4 + wrow0 * 8;
    float4* wlds = &sX[wid * 512];

    // Swizzled layout (R2-verified): chunk (row, c) of the panel lives at
    // slot row*8 + (c ^ (row&7)). global_load_lds writes linearly
    // (slot s = it*64 + lane), so the SOURCE is pre-swizzled:
    // s holds row = it*8 + (lane>>3), c = (lane&7) ^ (lane>>3).
    const int lrow = lane >> 3;              // 0..7
    const int lsrc = lrow * 8 + ((lane & 7) ^ lrow);   // it-independent part

    #pragma unroll
    for (int it = 0; it < 8; ++it) {
        __builtin_amdgcn_global_load_lds(
            (const __attribute__((address_space(1))) void*)(src0 + it * 64 + lsrc),
            (__attribute__((address_space(3))) void*)(wlds + it * 64),
            16, 0, 0);
    }
    // Per-wave wait: loads' LDS writes retired when vmcnt hits 0. No barrier.
    asm volatile("s_waitcnt vmcnt(0)" ::: "memory");
    __builtin_amdgcn_sched_barrier(0);

    // Own row (row == lane of this wave's panel): 8 x ds_read_b128, XOR-inv.
    const int r7 = lane & 7;
    float xr[T];
    #pragma unroll
    for (int k = 0; k < 8; ++k) {
        const float4 v = wlds[lane * 8 + (k ^ r7)];
        xr[4*k+0] = v.x; xr[4*k+1] = v.y; xr[4*k+2] = v.z; xr[4*k+3] = v.w;
    }

    // Triangular FMA; W/b wave-uniform -> s_load + SGPR operand (R1-proven).
    float acc[T];
    #pragma unroll
    for (int t = 0; t < T; ++t) {
        float a = b[t];
        #pragma unroll
        for (int j = 0; j <= t; ++j)
            a = fmaf(W[t * T + j], xr[j], a);
        acc[t] = a;
    }

    // Writeback own row into the same swizzled slots.
    #pragma unroll
    for (int k = 0; k < 8; ++k)
        wlds[lane * 8 + (k ^ r7)] =
            make_float4(acc[4*k+0], acc[4*k+1], acc[4*k+2], acc[4*k+3]);

    // Wave-synchronous cross-lane handoff: all lanes executed the writes
    // above (program order), lgkmcnt(0) retires them; reads below are safe.
    asm volatile("s_waitcnt lgkmcnt(0)" ::: "memory");
    __builtin_amdgcn_sched_barrier(0);

    // Coalesced stage-out. Out chunk idx = it*64+lane has row = it*8+lrow,
    // c = lane&7 -> swizzled slot = it*64 + lsrc (same formula as source).
    #pragma unroll
    for (int it = 0; it < 8; ++it)
        dst0[it * 64 + lane] = wlds[it * 64 + lsrc];
}

extern "C" void kernel_launch(void* const* d_in, const int* in_sizes, int n_in,
                              void* d_out, int out_size, void* d_ws, size_t ws_size,
                              hipStream_t stream) {
    const float* x  = (const float*)d_in[0];   // [B, 32]
    const float* W  = (const float*)d_in[1];   // [32, 32] (lower-tri used)
    const float* b  = (const float*)d_in[2];   // [32]
    float* out      = (float*)d_out;           // [B, 32]

    const int batch = in_sizes[0] / T;         // 1048576
    const int grid  = batch / ROWS;            // 4096 blocks
    triu_kernel<<<grid, 256, 0, stream>>>(x, W, b, out);
}